// Round 2
// 352.232 us; speedup vs baseline: 1.0764x; 1.0764x over previous
//
#include <hip/hip_runtime.h>
#include <hip/hip_bf16.h>
#include <math.h>

// x (2,128,512,512) f32.
//   s = sum_c x ; edge = sum_k |conv3x3(s, sobel_k)| ; out = maxpool2x2(edge)
//   broadcast over all 128 channels.  HBM floor: 268MB rd + 67MB wr ~= 51us.
//
// Pipeline (fused vs previous 4-dispatch version: the k1->part->k1b round
// trip moved an extra 16 MB; 512 blocks x 4 waves with 8 outstanding float4
// loads/thread is already enough in-flight bytes to saturate HBM, so the
// 4-group partial split bought no bandwidth):
//   memset  : zero padded s-plane (2.1 MB)
//   k1      : full 128-channel sum -> zero-padded s (stride 520, +1 row, +4 col)
//   k2      : branchless sobel+abs-sum+2x2maxpool, broadcast-store 64 MB

#define N 2
#define C 128
#define H 512
#define W 512
#define HW (H * W)
#define PH 256
#define PW 256
#define PHW (PH * PW)

#define NHW4 (N * HW / 4)          // 131072 float4 sites
#define SW 520                     // padded row stride (floats)
#define SR 514                     // padded rows
#define SPLANE (SR * SW)           // floats per padded plane

// native 4-float vector: __builtin_nontemporal_* requires a scalar/vector
// type, not HIP_vector_type<float,4>.
typedef float v4f __attribute__((ext_vector_type(4)));

// ---------- k1: full channel sum, written directly into padded plane -------
__global__ void __launch_bounds__(256) ksum_pad(const float* __restrict__ x,
                                                float* __restrict__ spad) {
    int idx = blockIdx.x * blockDim.x + threadIdx.x;   // 0 .. NHW4-1
    int n   = idx >> 16;                               // /65536 (HW/4 per image)
    int sp  = idx & 65535;
    const v4f* xp = (const v4f*)(x + (size_t)n * C * HW) + sp;
    v4f acc = (v4f)(0.f);
#pragma unroll 8
    for (int c = 0; c < C; ++c) {
        v4f v = __builtin_nontemporal_load(&xp[(size_t)c * (HW / 4)]);
        acc += v;
    }
    int r  = sp >> 7;            // / (W/4)
    int c4 = (sp & 127) << 2;    // original col
    // padded position: row r -> r+1, col c -> c+4  (stride SW)
    *(v4f*)(spad + (size_t)n * SPLANE + (size_t)(r + 1) * SW + (c4 + 4)) = acc;
}

// ------- k2: sobel-edge + 2x2 maxpool + channel broadcast (branchless) -----
__global__ void __launch_bounds__(256) kedge_pool_bcast(const float* __restrict__ spad,
                                                        float* __restrict__ out) {
    int idx = blockIdx.x * blockDim.x + threadIdx.x;   // 0 .. N*PH*(PW/4)-1
    int n   = idx / (PH * (PW / 4));
    int r   = idx % (PH * (PW / 4));
    int ph  = r / (PW / 4);
    int pw4 = (r % (PW / 4)) * 4;

    // original s-rows 2ph-1 .. 2ph+2 -> padded rows 2ph .. 2ph+3
    // original cols 2*pw4-1 .. 2*pw4+8 -> padded cols 2*pw4+3 .. 2*pw4+12
    const float* sp = spad + (size_t)n * SPLANE + (size_t)(2 * ph) * SW + (2 * pw4 + 3);

    float v[4][10];
#pragma unroll
    for (int i = 0; i < 4; ++i)
#pragma unroll
        for (int j = 0; j < 10; ++j)
            v[i][j] = sp[(size_t)i * SW + j];

    float pool[4];
#pragma unroll
    for (int q = 0; q < 4; ++q) {
        float m = 0.f;   // edge >= 0
#pragma unroll
        for (int a = 0; a < 2; ++a) {
#pragma unroll
            for (int b = 0; b < 2; ++b) {
                int jb = 2 * q + b;
                float p00 = v[a    ][jb], p01 = v[a    ][jb + 1], p02 = v[a    ][jb + 2];
                float p10 = v[a + 1][jb],                         p12 = v[a + 1][jb + 2];
                float p20 = v[a + 2][jb], p21 = v[a + 2][jb + 1], p22 = v[a + 2][jb + 2];
                float e0 = -p00 + p02 - 2.f * p10 + 2.f * p12 - p20 + p22;
                float e1 =  p00 + 2.f * p01 + p02 - p20 - 2.f * p21 - p22;
                float e2 = 2.f * p00 + p01 + p10 - p12 - p21 - 2.f * p22;
                float e3 = -p01 - 2.f * p02 + p10 - p12 + 2.f * p20 + p21;
                float edge = fabsf(e0) + fabsf(e1) + fabsf(e2) + fabsf(e3);
                m = fmaxf(m, edge);
            }
        }
        pool[q] = m;
    }
    v4f pv = (v4f){pool[0], pool[1], pool[2], pool[3]};

    int cbase = blockIdx.y * 16;   // gridDim.y = 8 -> 128 channels
    size_t base = (size_t)n * C * PHW + (size_t)cbase * PHW + (size_t)ph * PW + pw4;
#pragma unroll
    for (int c = 0; c < 16; ++c)
        __builtin_nontemporal_store(pv, (v4f*)(out + base + (size_t)c * PHW));
}

extern "C" void kernel_launch(void* const* d_in, const int* in_sizes, int n_in,
                              void* d_out, int out_size, void* d_ws, size_t ws_size,
                              hipStream_t stream) {
    const float* x = (const float*)d_in[0];
    float* out  = (float*)d_out;
    float* spad = (float*)d_ws;                         // N*SPLANE*4 ~= 2.14 MB

    // zero the padded s-plane (borders must be 0; ws is poisoned each launch)
    (void)hipMemsetAsync(spad, 0, (size_t)N * SPLANE * sizeof(float), stream);

    // k1: 512 blocks (2/CU, 8 waves/CU): 268 MB read, 2.1 MB write
    ksum_pad<<<dim3(NHW4 / 256), dim3(256), 0, stream>>>(x, spad);

    // k2: cached reads, 67 MB coalesced write
    kedge_pool_bcast<<<dim3((N * PH * (PW / 4)) / 256, 8), dim3(256), 0, stream>>>(spad, out);
}

// Round 3
// 350.695 us; speedup vs baseline: 1.0811x; 1.0044x over previous
//
#include <hip/hip_runtime.h>
#include <hip/hip_bf16.h>
#include <math.h>

// x (2,128,512,512) f32.
//   s = sum_c x ; edge = sum_k |conv3x3(s, sobel_k)| ; out = maxpool2x2(edge)
//   broadcast over all 128 channels.  HBM floor: 268MB rd + 67MB wr ~= 51us.
//
// Pipeline (2 dispatches, no memset):
//   k1 : full 128-channel sum -> zero-padded s (stride 520, +1 row, +4 col).
//        First 4128 threads also zero the only border cells k2 ever reads
//        (row 0, row 513, col 3, col 516 per plane) -- replaces the 2.1 MB
//        memset dispatch.  Workspace is poisoned each launch, so every cell
//        k2 reads must be written here.
//   k2 : branchless sobel+abs-sum+2x2maxpool, broadcast-store 64 MB.

#define N 2
#define C 128
#define H 512
#define W 512
#define HW (H * W)
#define PH 256
#define PW 256
#define PHW (PH * PW)

#define NHW4 (N * HW / 4)          // 131072 float4 sites
#define SW 520                     // padded row stride (floats)
#define SR 514                     // padded rows
#define SPLANE (SR * SW)           // floats per padded plane

// border cells per plane that k2 reads: rows 0 and 513 (520 each),
// plus cols 3 and 516 for rows 1..512 (2*512)
#define BORDER_PER_PLANE (2 * SW + 2 * H)   // 2064

// native 4-float vector: __builtin_nontemporal_* requires a scalar/vector
// type, not HIP_vector_type<float,4>.
typedef float v4f __attribute__((ext_vector_type(4)));

// ---------- k1: full channel sum, written directly into padded plane -------
__global__ void __launch_bounds__(256) ksum_pad(const float* __restrict__ x,
                                                float* __restrict__ spad) {
    int idx = blockIdx.x * blockDim.x + threadIdx.x;   // 0 .. NHW4-1

    // zero the border cells k2 reads (replaces memset dispatch)
    if (idx < N * BORDER_PER_PLANE) {
        int p = idx / BORDER_PER_PLANE;
        int u = idx % BORDER_PER_PLANE;
        float* plane = spad + (size_t)p * SPLANE;
        int rr, cc;
        if (u < SW)          { rr = 0;      cc = u; }
        else if (u < 2 * SW) { rr = SR - 1; cc = u - SW; }
        else { int w = u - 2 * SW; rr = 1 + (w >> 1); cc = (w & 1) ? 516 : 3; }
        plane[(size_t)rr * SW + cc] = 0.f;
    }

    int n   = idx >> 16;                               // /65536 (HW/4 per image)
    int sp  = idx & 65535;
    const v4f* xp = (const v4f*)(x + (size_t)n * C * HW) + sp;
    v4f acc = (v4f)(0.f);
#pragma unroll 8
    for (int c = 0; c < C; ++c) {
        v4f v = __builtin_nontemporal_load(&xp[(size_t)c * (HW / 4)]);
        acc += v;
    }
    int r  = sp >> 7;            // / (W/4)
    int c4 = (sp & 127) << 2;    // original col
    // padded position: row r -> r+1, col c -> c+4  (stride SW)
    *(v4f*)(spad + (size_t)n * SPLANE + (size_t)(r + 1) * SW + (c4 + 4)) = acc;
}

// ------- k2: sobel-edge + 2x2 maxpool + channel broadcast (branchless) -----
__global__ void __launch_bounds__(256) kedge_pool_bcast(const float* __restrict__ spad,
                                                        float* __restrict__ out) {
    int idx = blockIdx.x * blockDim.x + threadIdx.x;   // 0 .. N*PH*(PW/4)-1
    int n   = idx / (PH * (PW / 4));
    int r   = idx % (PH * (PW / 4));
    int ph  = r / (PW / 4);
    int pw4 = (r % (PW / 4)) * 4;

    // original s-rows 2ph-1 .. 2ph+2 -> padded rows 2ph .. 2ph+3
    // original cols 2*pw4-1 .. 2*pw4+8 -> padded cols 2*pw4+3 .. 2*pw4+12
    const float* sp = spad + (size_t)n * SPLANE + (size_t)(2 * ph) * SW + (2 * pw4 + 3);

    float v[4][10];
#pragma unroll
    for (int i = 0; i < 4; ++i)
#pragma unroll
        for (int j = 0; j < 10; ++j)
            v[i][j] = sp[(size_t)i * SW + j];

    float pool[4];
#pragma unroll
    for (int q = 0; q < 4; ++q) {
        float m = 0.f;   // edge >= 0
#pragma unroll
        for (int a = 0; a < 2; ++a) {
#pragma unroll
            for (int b = 0; b < 2; ++b) {
                int jb = 2 * q + b;
                float p00 = v[a    ][jb], p01 = v[a    ][jb + 1], p02 = v[a    ][jb + 2];
                float p10 = v[a + 1][jb],                         p12 = v[a + 1][jb + 2];
                float p20 = v[a + 2][jb], p21 = v[a + 2][jb + 1], p22 = v[a + 2][jb + 2];
                float e0 = -p00 + p02 - 2.f * p10 + 2.f * p12 - p20 + p22;
                float e1 =  p00 + 2.f * p01 + p02 - p20 - 2.f * p21 - p22;
                float e2 = 2.f * p00 + p01 + p10 - p12 - p21 - 2.f * p22;
                float e3 = -p01 - 2.f * p02 + p10 - p12 + 2.f * p20 + p21;
                float edge = fabsf(e0) + fabsf(e1) + fabsf(e2) + fabsf(e3);
                m = fmaxf(m, edge);
            }
        }
        pool[q] = m;
    }
    v4f pv = (v4f){pool[0], pool[1], pool[2], pool[3]};

    int cbase = blockIdx.y * 16;   // gridDim.y = 8 -> 128 channels
    size_t base = (size_t)n * C * PHW + (size_t)cbase * PHW + (size_t)ph * PW + pw4;
#pragma unroll
    for (int c = 0; c < 16; ++c)
        __builtin_nontemporal_store(pv, (v4f*)(out + base + (size_t)c * PHW));
}

extern "C" void kernel_launch(void* const* d_in, const int* in_sizes, int n_in,
                              void* d_out, int out_size, void* d_ws, size_t ws_size,
                              hipStream_t stream) {
    const float* x = (const float*)d_in[0];
    float* out  = (float*)d_out;
    float* spad = (float*)d_ws;                         // N*SPLANE*4 ~= 2.14 MB

    // k1: 512 blocks (2/CU, 8 waves/CU): 268 MB read, 2.1 MB write (+ borders)
    ksum_pad<<<dim3(NHW4 / 256), dim3(256), 0, stream>>>(x, spad);

    // k2: L2-hot spad reads, 67 MB coalesced nontemporal write
    kedge_pool_bcast<<<dim3((N * PH * (PW / 4)) / 256, 8), dim3(256), 0, stream>>>(spad, out);
}